// Round 2
// baseline (1494.376 us; speedup 1.0000x reference)
//
#include <hip/hip_runtime.h>
#include <cstdint>

#define NA 65536
#define NB 262144
#define MAXNB 6
#define H 256
#define BF 147
#define AF 133
#define NM 2048

typedef unsigned int u32;

// bf16 helpers (manual, RNE)
__device__ __forceinline__ u32 pack_bf2(float a, float b) {
    u32 ua = __float_as_uint(a); ua = (ua + 0x7FFFu + ((ua >> 16) & 1u)) >> 16;
    u32 ub = __float_as_uint(b); ub = (ub + 0x7FFFu + ((ub >> 16) & 1u)) >> 16;
    return ua | (ub << 16);
}
__device__ __forceinline__ float bf_lo(u32 u) { return __uint_as_float(u << 16); }
__device__ __forceinline__ float bf_hi(u32 u) { return __uint_as_float(u & 0xFFFF0000u); }

// ---------------------------------------------------------------------------
// K1: inp[NB,256] = f_bonds[NB,147] @ W_i[147,256] -> stored as bf16 (pre-act)
// ---------------------------------------------------------------------------
__global__ __launch_bounds__(256) void k_gemm_wi(const float* __restrict__ X,
                                                 const float* __restrict__ W,
                                                 u32* __restrict__ outb) {
    __shared__ float xs[64 * 148];
    const int blk = blockIdx.x;
    const int tid = threadIdx.x;
    const float* src = X + (size_t)blk * 64 * BF;
    for (int idx = tid; idx < 64 * BF; idx += 256) {
        int r = idx / BF, c = idx - r * BF;
        xs[r * 148 + c] = src[idx];
    }
    __syncthreads();
    const int tc = tid & 31, tr = tid >> 5;
    const int row0 = tr * 8, col0 = tc * 8;
    float acc[8][8] = {};
    for (int kb = 0; kb < 36; ++kb) {  // k = 0..143
        const int k = kb * 4;
        float4 xv[8];
#pragma unroll
        for (int r = 0; r < 8; ++r)
            xv[r] = *(const float4*)&xs[(row0 + r) * 148 + k];
#pragma unroll
        for (int kk = 0; kk < 4; ++kk) {
            float4 wa = *(const float4*)&W[(size_t)(k + kk) * 256 + col0];
            float4 wb = *(const float4*)&W[(size_t)(k + kk) * 256 + col0 + 4];
            float w[8] = {wa.x, wa.y, wa.z, wa.w, wb.x, wb.y, wb.z, wb.w};
#pragma unroll
            for (int r = 0; r < 8; ++r) {
                float x = ((const float*)&xv[r])[kk];
#pragma unroll
                for (int c = 0; c < 8; ++c) acc[r][c] = fmaf(x, w[c], acc[r][c]);
            }
        }
    }
    for (int k = 144; k < 147; ++k) {  // tail
        float w[8];
#pragma unroll
        for (int c = 0; c < 8; ++c) w[c] = W[(size_t)k * 256 + col0 + c];
#pragma unroll
        for (int r = 0; r < 8; ++r) {
            float x = xs[(row0 + r) * 148 + k];
#pragma unroll
            for (int c = 0; c < 8; ++c) acc[r][c] = fmaf(x, w[c], acc[r][c]);
        }
    }
#pragma unroll
    for (int r = 0; r < 8; ++r) {
        size_t o = ((size_t)blk * 64 + row0 + r) * 256 + col0;  // element index, mult of 8
        uint4 pv;
        pv.x = pack_bf2(acc[r][0], acc[r][1]);
        pv.y = pack_bf2(acc[r][2], acc[r][3]);
        pv.z = pack_bf2(acc[r][4], acc[r][5]);
        pv.w = pack_bf2(acc[r][6], acc[r][7]);
        *(uint4*)&outb[o >> 1] = pv;
    }
}

// ---------------------------------------------------------------------------
// K2: agg[a,:] = sum_j msg(a2b[a][j])[:]   (bf16 msg; RELU_SRC: relu on gather)
// One wave per atom, 4 atoms per block; 512B coalesced row gathers.
// ---------------------------------------------------------------------------
template <bool RELU_SRC>
__global__ __launch_bounds__(256) void k_agg(const u32* __restrict__ msgb,
                                             const int* __restrict__ a2b,
                                             float* __restrict__ agg) {
    const int tid = threadIdx.x;
    const int lane = tid & 63, wv = tid >> 6;
    const int a = blockIdx.x * 4 + wv;
    float4 s = {0.f, 0.f, 0.f, 0.f};
#pragma unroll
    for (int j = 0; j < MAXNB; ++j) {
        int b = a2b[a * MAXNB + j];
        uint2 mv = *(const uint2*)&msgb[(size_t)b * 128 + lane * 2];
        float e0 = bf_lo(mv.x), e1 = bf_hi(mv.x), e2 = bf_lo(mv.y), e3 = bf_hi(mv.y);
        if (RELU_SRC) {
            e0 = fmaxf(e0, 0.f); e1 = fmaxf(e1, 0.f);
            e2 = fmaxf(e2, 0.f); e3 = fmaxf(e3, 0.f);
        }
        s.x += e0; s.y += e1; s.z += e2; s.w += e3;
    }
    *(float4*)&agg[(size_t)a * 256 + lane * 4] = s;
}

// ---------------------------------------------------------------------------
// K3: msg_out = relu(inp + (agg[b2a] - msg(b2revb)) @ W_m)   (bf16 in/out)
// ---------------------------------------------------------------------------
template <bool RELU_SRC>
__global__ __launch_bounds__(256) void k_msg_update(
    const u32* __restrict__ inpb, const float* __restrict__ agg,
    const u32* __restrict__ msgb_in, const int* __restrict__ b2a,
    const int* __restrict__ b2revb, const float* __restrict__ Wm,
    u32* __restrict__ msgb_out) {
    __shared__ float xs[64 * 260];
    const int blk = blockIdx.x;
    const int tid = threadIdx.x;
    const int lane = tid & 63, wv = tid >> 6;
    for (int r = wv; r < 64; r += 4) {
        const int b = blk * 64 + r;
        const int a = b2a[b];
        const int rb = b2revb[b];
        float4 g = *(const float4*)&agg[(size_t)a * 256 + lane * 4];
        uint2 mv = *(const uint2*)&msgb_in[(size_t)rb * 128 + lane * 2];
        float m0 = bf_lo(mv.x), m1 = bf_hi(mv.x), m2 = bf_lo(mv.y), m3 = bf_hi(mv.y);
        if (RELU_SRC) {
            m0 = fmaxf(m0, 0.f); m1 = fmaxf(m1, 0.f);
            m2 = fmaxf(m2, 0.f); m3 = fmaxf(m3, 0.f);
        }
        float4 d = {g.x - m0, g.y - m1, g.z - m2, g.w - m3};
        *(float4*)&xs[r * 260 + lane * 4] = d;
    }
    __syncthreads();
    const int tc = tid & 31, tr = tid >> 5;
    const int row0 = tr * 8, col0 = tc * 8;
    float acc[8][8] = {};
    for (int kb = 0; kb < 64; ++kb) {
        const int k = kb * 4;
        float4 xv[8];
#pragma unroll
        for (int r = 0; r < 8; ++r)
            xv[r] = *(const float4*)&xs[(row0 + r) * 260 + k];
#pragma unroll
        for (int kk = 0; kk < 4; ++kk) {
            float4 wa = *(const float4*)&Wm[(size_t)(k + kk) * 256 + col0];
            float4 wb = *(const float4*)&Wm[(size_t)(k + kk) * 256 + col0 + 4];
            float w[8] = {wa.x, wa.y, wa.z, wa.w, wb.x, wb.y, wb.z, wb.w};
#pragma unroll
            for (int r = 0; r < 8; ++r) {
                float x = ((const float*)&xv[r])[kk];
#pragma unroll
                for (int c = 0; c < 8; ++c) acc[r][c] = fmaf(x, w[c], acc[r][c]);
            }
        }
    }
#pragma unroll
    for (int r = 0; r < 8; ++r) {
        size_t o = ((size_t)blk * 64 + row0 + r) * 256 + col0;
        uint4 iv = *(const uint4*)&inpb[o >> 1];
        float i0 = bf_lo(iv.x), i1 = bf_hi(iv.x), i2 = bf_lo(iv.y), i3 = bf_hi(iv.y);
        float i4 = bf_lo(iv.z), i5 = bf_hi(iv.z), i6 = bf_lo(iv.w), i7 = bf_hi(iv.w);
        uint4 pv;
        pv.x = pack_bf2(fmaxf(acc[r][0] + i0, 0.f), fmaxf(acc[r][1] + i1, 0.f));
        pv.y = pack_bf2(fmaxf(acc[r][2] + i2, 0.f), fmaxf(acc[r][3] + i3, 0.f));
        pv.z = pack_bf2(fmaxf(acc[r][4] + i4, 0.f), fmaxf(acc[r][5] + i5, 0.f));
        pv.w = pack_bf2(fmaxf(acc[r][6] + i6, 0.f), fmaxf(acc[r][7] + i7, 0.f));
        *(uint4*)&msgb_out[o >> 1] = pv;
    }
}

// ---------------------------------------------------------------------------
// K4: atom_h = relu([f_atoms | a_message] @ W_a + b_a)   (fp32)
// ---------------------------------------------------------------------------
__global__ __launch_bounds__(256) void k_atomh(
    const float* __restrict__ f_atoms, const float* __restrict__ amsg,
    const float* __restrict__ Wa, const float* __restrict__ ba,
    float* __restrict__ atom_h) {
    __shared__ float xs[32 * 392];
    const int blk = blockIdx.x;
    const int tid = threadIdx.x;
    const float* srcA = f_atoms + (size_t)blk * 32 * AF;
    for (int idx = tid; idx < 32 * AF; idx += 256) {
        int r = idx / AF, c = idx - r * AF;
        xs[r * 392 + c] = srcA[idx];
    }
    const float* srcM = amsg + (size_t)blk * 32 * 256;
    for (int idx = tid; idx < 32 * 256; idx += 256) {
        int r = idx >> 8, c = idx & 255;
        xs[r * 392 + AF + c] = srcM[idx];
    }
    __syncthreads();
    const int tc = tid & 31, tr = tid >> 5;
    const int row0 = tr * 4, col0 = tc * 8;
    float acc[4][8] = {};
    for (int kb = 0; kb < 97; ++kb) {  // k = 0..387
        const int k = kb * 4;
        float4 xv[4];
#pragma unroll
        for (int r = 0; r < 4; ++r)
            xv[r] = *(const float4*)&xs[(row0 + r) * 392 + k];
#pragma unroll
        for (int kk = 0; kk < 4; ++kk) {
            float4 wa = *(const float4*)&Wa[(size_t)(k + kk) * 256 + col0];
            float4 wb = *(const float4*)&Wa[(size_t)(k + kk) * 256 + col0 + 4];
            float w[8] = {wa.x, wa.y, wa.z, wa.w, wb.x, wb.y, wb.z, wb.w};
#pragma unroll
            for (int r = 0; r < 4; ++r) {
                float x = ((const float*)&xv[r])[kk];
#pragma unroll
                for (int c = 0; c < 8; ++c) acc[r][c] = fmaf(x, w[c], acc[r][c]);
            }
        }
    }
    {  // tail k = 388
        const int k = 388;
        float w[8];
#pragma unroll
        for (int c = 0; c < 8; ++c) w[c] = Wa[(size_t)k * 256 + col0 + c];
#pragma unroll
        for (int r = 0; r < 4; ++r) {
            float x = xs[(row0 + r) * 392 + k];
#pragma unroll
            for (int c = 0; c < 8; ++c) acc[r][c] = fmaf(x, w[c], acc[r][c]);
        }
    }
    float4 b0 = *(const float4*)&ba[col0];
    float4 b1 = *(const float4*)&ba[col0 + 4];
#pragma unroll
    for (int r = 0; r < 4; ++r) {
        size_t o = ((size_t)blk * 32 + row0 + r) * 256 + col0;
        float4 v0 = {fmaxf(acc[r][0] + b0.x, 0.f), fmaxf(acc[r][1] + b0.y, 0.f),
                     fmaxf(acc[r][2] + b0.z, 0.f), fmaxf(acc[r][3] + b0.w, 0.f)};
        float4 v1 = {fmaxf(acc[r][4] + b1.x, 0.f), fmaxf(acc[r][5] + b1.y, 0.f),
                     fmaxf(acc[r][6] + b1.z, 0.f), fmaxf(acc[r][7] + b1.w, 0.f)};
        *(float4*)&atom_h[o] = v0;
        *(float4*)&atom_h[o + 4] = v1;
    }
}

// ---------------------------------------------------------------------------
// K5: per-molecule mean readout; mol_index sorted -> binary search range.
// ---------------------------------------------------------------------------
__global__ __launch_bounds__(256) void k_readout(const float* __restrict__ atom_h,
                                                 const int* __restrict__ mol_index,
                                                 float* __restrict__ out) {
    __shared__ int s_lo, s_hi;
    const int m = blockIdx.x;
    const int tid = threadIdx.x;
    if (tid == 0) {
        int lo = 0, hi = NA;
        while (lo < hi) { int mid = (lo + hi) >> 1; if (mol_index[mid] < m) lo = mid + 1; else hi = mid; }
        s_lo = lo;
        int lo2 = lo, hi2 = NA;
        while (lo2 < hi2) { int mid = (lo2 + hi2) >> 1; if (mol_index[mid] < m + 1) lo2 = mid + 1; else hi2 = mid; }
        s_hi = lo2;
    }
    __syncthreads();
    const int lo = s_lo, hi = s_hi;
    float s = 0.f;
    for (int a = lo; a < hi; ++a) s += atom_h[(size_t)a * 256 + tid];
    float cnt = (float)(hi - lo);
    out[(size_t)m * 256 + tid] = s / fmaxf(cnt, 1.0f);
}

// ---------------------------------------------------------------------------
extern "C" void kernel_launch(void* const* d_in, const int* in_sizes, int n_in,
                              void* d_out, int out_size, void* d_ws, size_t ws_size,
                              hipStream_t stream) {
    const float* f_atoms = (const float*)d_in[0];
    const float* f_bonds = (const float*)d_in[1];
    const float* W_i     = (const float*)d_in[2];
    const float* W_m     = (const float*)d_in[3];
    const float* W_a     = (const float*)d_in[4];
    const float* b_a     = (const float*)d_in[5];
    const int* a2b       = (const int*)d_in[6];
    const int* b2a       = (const int*)d_in[7];
    const int* b2revb    = (const int*)d_in[8];
    const int* mol_index = (const int*)d_in[9];
    float* out = (float*)d_out;

    // bf16 big buffers: 3 x 128MB; agg fp32 64MB; atom_h aliases msg1.
    const size_t SZ_BH2 = (size_t)NB * H * 2;       // 134,217,728
    const size_t SZ_AH4 = (size_t)NA * H * 4;       // 67,108,864
    const size_t NEEDED = 3 * SZ_BH2 + SZ_AH4;      // 469,762,048
    if (ws_size < NEEDED) return;  // diagnostic guard: clean absmax-fail instead of fault

    char* ws = (char*)d_ws;
    u32* inp   = (u32*)(ws);
    u32* msg1  = (u32*)(ws + SZ_BH2);
    u32* msg2  = (u32*)(ws + 2 * SZ_BH2);
    float* agg = (float*)(ws + 3 * SZ_BH2);
    float* ath = (float*)(ws + SZ_BH2);  // alias msg1 (dead by K4)

    // inp = f_bonds @ W_i (pre-activation, bf16); message0 = relu(inp) virtual
    k_gemm_wi<<<NB / 64, 256, 0, stream>>>(f_bonds, W_i, inp);

    // step 1
    k_agg<true><<<NA / 4, 256, 0, stream>>>(inp, a2b, agg);
    k_msg_update<true><<<NB / 64, 256, 0, stream>>>(inp, agg, inp, b2a, b2revb, W_m, msg1);

    // step 2
    k_agg<false><<<NA / 4, 256, 0, stream>>>(msg1, a2b, agg);
    k_msg_update<false><<<NB / 64, 256, 0, stream>>>(inp, agg, msg1, b2a, b2revb, W_m, msg2);

    // atom aggregation + W_a + relu
    k_agg<false><<<NA / 4, 256, 0, stream>>>(msg2, a2b, agg);
    k_atomh<<<NA / 32, 256, 0, stream>>>(f_atoms, agg, W_a, b_a, ath);

    // per-molecule mean readout
    k_readout<<<NM, 256, 0, stream>>>(ath, mol_index, out);
}

// Round 3
// 894.979 us; speedup vs baseline: 1.6697x; 1.6697x over previous
//
#include <hip/hip_runtime.h>
#include <cstdint>

#define NA 65536
#define NB 262144
#define MAXNB 6
#define H 256
#define BF 147
#define AF 133
#define NM 2048

typedef unsigned int u32;
typedef __attribute__((ext_vector_type(8))) short bf16x8;
typedef __attribute__((ext_vector_type(4))) float f32x4;

// bf16 helpers (manual, RNE)
__device__ __forceinline__ u32 pack_bf2(float a, float b) {
    u32 ua = __float_as_uint(a); ua = (ua + 0x7FFFu + ((ua >> 16) & 1u)) >> 16;
    u32 ub = __float_as_uint(b); ub = (ub + 0x7FFFu + ((ub >> 16) & 1u)) >> 16;
    return ua | (ub << 16);
}
__device__ __forceinline__ unsigned short bf1(float a) {
    u32 ua = __float_as_uint(a); return (unsigned short)((ua + 0x7FFFu + ((ua >> 16) & 1u)) >> 16);
}
__device__ __forceinline__ float bf_lo(u32 u) { return __uint_as_float(u << 16); }
__device__ __forceinline__ float bf_hi(u32 u) { return __uint_as_float(u & 0xFFFF0000u); }

// ---------------------------------------------------------------------------
// K0: pack W_m[256][256] fp32 -> Wp bf16 fragment layout.
// Wp element (kbg, col) holds 8 bf16: W[kbg*8 + j][col], j=0..7, as uint4.
// kbg = kb*4 + g, kb = K/32 block, g = lane>>4 group.
// ---------------------------------------------------------------------------
__global__ __launch_bounds__(256) void k_pack_wm(const float* __restrict__ W,
                                                 uint4* __restrict__ Wp) {
    int t = blockIdx.x * 256 + threadIdx.x;  // 0..8191
    int kbg = t >> 8;
    int col = t & 255;
    int k0 = kbg * 8;
    uint4 o;
    o.x = pack_bf2(W[(size_t)(k0 + 0) * 256 + col], W[(size_t)(k0 + 1) * 256 + col]);
    o.y = pack_bf2(W[(size_t)(k0 + 2) * 256 + col], W[(size_t)(k0 + 3) * 256 + col]);
    o.z = pack_bf2(W[(size_t)(k0 + 4) * 256 + col], W[(size_t)(k0 + 5) * 256 + col]);
    o.w = pack_bf2(W[(size_t)(k0 + 6) * 256 + col], W[(size_t)(k0 + 7) * 256 + col]);
    Wp[t] = o;
}

// ---------------------------------------------------------------------------
// K1: inp[NB,256] = f_bonds[NB,147] @ W_i[147,256] -> stored as bf16 (pre-act)
// ---------------------------------------------------------------------------
__global__ __launch_bounds__(256) void k_gemm_wi(const float* __restrict__ X,
                                                 const float* __restrict__ W,
                                                 u32* __restrict__ outb) {
    __shared__ float xs[64 * 148];
    const int blk = blockIdx.x;
    const int tid = threadIdx.x;
    const float* src = X + (size_t)blk * 64 * BF;
    for (int idx = tid; idx < 64 * BF; idx += 256) {
        int r = idx / BF, c = idx - r * BF;
        xs[r * 148 + c] = src[idx];
    }
    __syncthreads();
    const int tc = tid & 31, tr = tid >> 5;
    const int row0 = tr * 8, col0 = tc * 8;
    float acc[8][8] = {};
    for (int kb = 0; kb < 36; ++kb) {  // k = 0..143
        const int k = kb * 4;
        float4 xv[8];
#pragma unroll
        for (int r = 0; r < 8; ++r)
            xv[r] = *(const float4*)&xs[(row0 + r) * 148 + k];
#pragma unroll
        for (int kk = 0; kk < 4; ++kk) {
            float4 wa = *(const float4*)&W[(size_t)(k + kk) * 256 + col0];
            float4 wb = *(const float4*)&W[(size_t)(k + kk) * 256 + col0 + 4];
            float w[8] = {wa.x, wa.y, wa.z, wa.w, wb.x, wb.y, wb.z, wb.w};
#pragma unroll
            for (int r = 0; r < 8; ++r) {
                float x = ((const float*)&xv[r])[kk];
#pragma unroll
                for (int c = 0; c < 8; ++c) acc[r][c] = fmaf(x, w[c], acc[r][c]);
            }
        }
    }
    for (int k = 144; k < 147; ++k) {  // tail
        float w[8];
#pragma unroll
        for (int c = 0; c < 8; ++c) w[c] = W[(size_t)k * 256 + col0 + c];
#pragma unroll
        for (int r = 0; r < 8; ++r) {
            float x = xs[(row0 + r) * 148 + k];
#pragma unroll
            for (int c = 0; c < 8; ++c) acc[r][c] = fmaf(x, w[c], acc[r][c]);
        }
    }
#pragma unroll
    for (int r = 0; r < 8; ++r) {
        size_t o = ((size_t)blk * 64 + row0 + r) * 256 + col0;
        uint4 pv;
        pv.x = pack_bf2(acc[r][0], acc[r][1]);
        pv.y = pack_bf2(acc[r][2], acc[r][3]);
        pv.z = pack_bf2(acc[r][4], acc[r][5]);
        pv.w = pack_bf2(acc[r][6], acc[r][7]);
        *(uint4*)&outb[o >> 1] = pv;
    }
}

// ---------------------------------------------------------------------------
// K2: agg[a,:] = sum_j msg(a2b[a][j])[:]   (bf16 msg; RELU_SRC: relu on gather)
// ---------------------------------------------------------------------------
template <bool RELU_SRC>
__global__ __launch_bounds__(256) void k_agg(const u32* __restrict__ msgb,
                                             const int* __restrict__ a2b,
                                             float* __restrict__ agg) {
    const int tid = threadIdx.x;
    const int lane = tid & 63, wv = tid >> 6;
    const int a = blockIdx.x * 4 + wv;
    float4 s = {0.f, 0.f, 0.f, 0.f};
#pragma unroll
    for (int j = 0; j < MAXNB; ++j) {
        int b = a2b[a * MAXNB + j];
        uint2 mv = *(const uint2*)&msgb[(size_t)b * 128 + lane * 2];
        float e0 = bf_lo(mv.x), e1 = bf_hi(mv.x), e2 = bf_lo(mv.y), e3 = bf_hi(mv.y);
        if (RELU_SRC) {
            e0 = fmaxf(e0, 0.f); e1 = fmaxf(e1, 0.f);
            e2 = fmaxf(e2, 0.f); e3 = fmaxf(e3, 0.f);
        }
        s.x += e0; s.y += e1; s.z += e2; s.w += e3;
    }
    *(float4*)&agg[(size_t)a * 256 + lane * 4] = s;
}

// ---------------------------------------------------------------------------
// K3 (MFMA): msg_out = relu(inp + (agg[b2a] - msg(b2revb)) @ W_m)
// 64-bond tile, 4 waves; wave w owns 64-col slice. 16x16x32 bf16 MFMA.
// A-tile in LDS bf16 [64][256] with XOR-swizzle on 16B chunks (T2).
// B from pre-packed Wp (L2-resident, coalesced 16B/lane).
// ---------------------------------------------------------------------------
template <bool RELU_SRC>
__global__ __launch_bounds__(256) void k_msg_update(
    const u32* __restrict__ inpb, const float* __restrict__ agg,
    const u32* __restrict__ msgb_in, const int* __restrict__ b2a,
    const int* __restrict__ b2revb, const uint4* __restrict__ Wp,
    u32* __restrict__ msgb_out) {
    __shared__ char xs[64 * 512];  // 32 KB bf16 [64 rows][256 cols]
    const int blk = blockIdx.x;
    const int tid = threadIdx.x;
    const int lane = tid & 63, wv = tid >> 6;
    const int rlo = lane & 15, g = lane >> 4;

    // ---- stage A-tile: diff = agg[b2a[b]] - relu?(msg[b2revb[b]]) -> bf16 LDS
    for (int r = wv; r < 64; r += 4) {
        const int b = blk * 64 + r;
        const int a = b2a[b];
        const int rb_ = b2revb[b];
        float4 gv = *(const float4*)&agg[(size_t)a * 256 + lane * 4];
        uint2 mv = *(const uint2*)&msgb_in[(size_t)rb_ * 128 + lane * 2];
        float m0 = bf_lo(mv.x), m1 = bf_hi(mv.x), m2 = bf_lo(mv.y), m3 = bf_hi(mv.y);
        if (RELU_SRC) {
            m0 = fmaxf(m0, 0.f); m1 = fmaxf(m1, 0.f);
            m2 = fmaxf(m2, 0.f); m3 = fmaxf(m3, 0.f);
        }
        uint2 pk;
        pk.x = pack_bf2(gv.x - m0, gv.y - m1);
        pk.y = pack_bf2(gv.z - m2, gv.w - m3);
        // logical byte col = lane*8; chunk16 = lane>>1; swizzle chunk ^ (row&7)
        int schunk = (lane >> 1) ^ (r & 7);
        *(uint2*)(xs + r * 512 + (schunk << 4) + (lane & 1) * 8) = pk;
    }
    __syncthreads();

    // ---- MFMA main loop: K=256 in 8 steps of 32
    f32x4 acc[4][4] = {};  // [row-block][col-block], rows rb*16, cols wv*64+cb*16
#pragma unroll
    for (int kb = 0; kb < 8; ++kb) {
        bf16x8 af[4], bf[4];
#pragma unroll
        for (int rb = 0; rb < 4; ++rb) {
            int row = rb * 16 + rlo;
            int schunk = (kb * 4 + g) ^ (row & 7);
            af[rb] = *(const bf16x8*)(xs + row * 512 + (schunk << 4));
        }
#pragma unroll
        for (int cb = 0; cb < 4; ++cb) {
            uint4 w = Wp[(size_t)(kb * 4 + g) * 256 + wv * 64 + cb * 16 + rlo];
            bf[cb] = *(const bf16x8*)&w;
        }
#pragma unroll
        for (int rb = 0; rb < 4; ++rb)
#pragma unroll
            for (int cb = 0; cb < 4; ++cb)
                acc[rb][cb] = __builtin_amdgcn_mfma_f32_16x16x32_bf16(
                    af[rb], bf[cb], acc[rb][cb], 0, 0, 0);
    }
    __syncthreads();  // all A-tile reads done; reuse xs for output transpose

    // ---- write D (bf16) into xs linear [64][256]
    // D mapping: row = rb*16 + g*4 + r, col = wv*64 + cb*16 + rlo
#pragma unroll
    for (int rb = 0; rb < 4; ++rb)
#pragma unroll
        for (int cb = 0; cb < 4; ++cb) {
#pragma unroll
            for (int r = 0; r < 4; ++r) {
                int row = rb * 16 + g * 4 + r;
                int col = wv * 64 + cb * 16 + rlo;
                ((unsigned short*)xs)[row * 256 + col] = bf1(acc[rb][cb][r]);
            }
        }
    __syncthreads();

    // ---- fused epilogue: out = relu(inp + D), coalesced bf16x8 per thread
#pragma unroll
    for (int i = 0; i < 8; ++i) {
        int e = (i * 256 + tid) * 8;       // element index in 64x256 tile
        int row = e >> 8, col = e & 255;
        uint4 dv = *(const uint4*)(xs + row * 512 + col * 2);
        size_t go = ((size_t)blk * 64 + row) * 256 + col;   // global element idx
        uint4 iv = *(const uint4*)&inpb[go >> 1];
        uint4 ov;
        ov.x = pack_bf2(fmaxf(bf_lo(dv.x) + bf_lo(iv.x), 0.f),
                        fmaxf(bf_hi(dv.x) + bf_hi(iv.x), 0.f));
        ov.y = pack_bf2(fmaxf(bf_lo(dv.y) + bf_lo(iv.y), 0.f),
                        fmaxf(bf_hi(dv.y) + bf_hi(iv.y), 0.f));
        ov.z = pack_bf2(fmaxf(bf_lo(dv.z) + bf_lo(iv.z), 0.f),
                        fmaxf(bf_hi(dv.z) + bf_hi(iv.z), 0.f));
        ov.w = pack_bf2(fmaxf(bf_lo(dv.w) + bf_lo(iv.w), 0.f),
                        fmaxf(bf_hi(dv.w) + bf_hi(iv.w), 0.f));
        *(uint4*)&msgb_out[go >> 1] = ov;
    }
}

// ---------------------------------------------------------------------------
// K4: atom_h = relu([f_atoms | a_message] @ W_a + b_a)   (fp32)
// ---------------------------------------------------------------------------
__global__ __launch_bounds__(256) void k_atomh(
    const float* __restrict__ f_atoms, const float* __restrict__ amsg,
    const float* __restrict__ Wa, const float* __restrict__ ba,
    float* __restrict__ atom_h) {
    __shared__ float xs[32 * 392];
    const int blk = blockIdx.x;
    const int tid = threadIdx.x;
    const float* srcA = f_atoms + (size_t)blk * 32 * AF;
    for (int idx = tid; idx < 32 * AF; idx += 256) {
        int r = idx / AF, c = idx - r * AF;
        xs[r * 392 + c] = srcA[idx];
    }
    const float* srcM = amsg + (size_t)blk * 32 * 256;
    for (int idx = tid; idx < 32 * 256; idx += 256) {
        int r = idx >> 8, c = idx & 255;
        xs[r * 392 + AF + c] = srcM[idx];
    }
    __syncthreads();
    const int tc = tid & 31, tr = tid >> 5;
    const int row0 = tr * 4, col0 = tc * 8;
    float acc[4][8] = {};
    for (int kb = 0; kb < 97; ++kb) {  // k = 0..387
        const int k = kb * 4;
        float4 xv[4];
#pragma unroll
        for (int r = 0; r < 4; ++r)
            xv[r] = *(const float4*)&xs[(row0 + r) * 392 + k];
#pragma unroll
        for (int kk = 0; kk < 4; ++kk) {
            float4 wa = *(const float4*)&Wa[(size_t)(k + kk) * 256 + col0];
            float4 wb = *(const float4*)&Wa[(size_t)(k + kk) * 256 + col0 + 4];
            float w[8] = {wa.x, wa.y, wa.z, wa.w, wb.x, wb.y, wb.z, wb.w};
#pragma unroll
            for (int r = 0; r < 4; ++r) {
                float x = ((const float*)&xv[r])[kk];
#pragma unroll
                for (int c = 0; c < 8; ++c) acc[r][c] = fmaf(x, w[c], acc[r][c]);
            }
        }
    }
    {  // tail k = 388
        const int k = 388;
        float w[8];
#pragma unroll
        for (int c = 0; c < 8; ++c) w[c] = Wa[(size_t)k * 256 + col0 + c];
#pragma unroll
        for (int r = 0; r < 4; ++r) {
            float x = xs[(row0 + r) * 392 + k];
#pragma unroll
            for (int c = 0; c < 8; ++c) acc[r][c] = fmaf(x, w[c], acc[r][c]);
        }
    }
    float4 b0 = *(const float4*)&ba[col0];
    float4 b1 = *(const float4*)&ba[col0 + 4];
#pragma unroll
    for (int r = 0; r < 4; ++r) {
        size_t o = ((size_t)blk * 32 + row0 + r) * 256 + col0;
        float4 v0 = {fmaxf(acc[r][0] + b0.x, 0.f), fmaxf(acc[r][1] + b0.y, 0.f),
                     fmaxf(acc[r][2] + b0.z, 0.f), fmaxf(acc[r][3] + b0.w, 0.f)};
        float4 v1 = {fmaxf(acc[r][4] + b1.x, 0.f), fmaxf(acc[r][5] + b1.y, 0.f),
                     fmaxf(acc[r][6] + b1.z, 0.f), fmaxf(acc[r][7] + b1.w, 0.f)};
        *(float4*)&atom_h[o] = v0;
        *(float4*)&atom_h[o + 4] = v1;
    }
}

// ---------------------------------------------------------------------------
// K5: per-molecule mean readout; mol_index sorted -> binary search range.
// ---------------------------------------------------------------------------
__global__ __launch_bounds__(256) void k_readout(const float* __restrict__ atom_h,
                                                 const int* __restrict__ mol_index,
                                                 float* __restrict__ out) {
    __shared__ int s_lo, s_hi;
    const int m = blockIdx.x;
    const int tid = threadIdx.x;
    if (tid == 0) {
        int lo = 0, hi = NA;
        while (lo < hi) { int mid = (lo + hi) >> 1; if (mol_index[mid] < m) lo = mid + 1; else hi = mid; }
        s_lo = lo;
        int lo2 = lo, hi2 = NA;
        while (lo2 < hi2) { int mid = (lo2 + hi2) >> 1; if (mol_index[mid] < m + 1) lo2 = mid + 1; else hi2 = mid; }
        s_hi = lo2;
    }
    __syncthreads();
    const int lo = s_lo, hi = s_hi;
    float s = 0.f;
    for (int a = lo; a < hi; ++a) s += atom_h[(size_t)a * 256 + tid];
    float cnt = (float)(hi - lo);
    out[(size_t)m * 256 + tid] = s / fmaxf(cnt, 1.0f);
}

// ---------------------------------------------------------------------------
extern "C" void kernel_launch(void* const* d_in, const int* in_sizes, int n_in,
                              void* d_out, int out_size, void* d_ws, size_t ws_size,
                              hipStream_t stream) {
    const float* f_atoms = (const float*)d_in[0];
    const float* f_bonds = (const float*)d_in[1];
    const float* W_i     = (const float*)d_in[2];
    const float* W_m     = (const float*)d_in[3];
    const float* W_a     = (const float*)d_in[4];
    const float* b_a     = (const float*)d_in[5];
    const int* a2b       = (const int*)d_in[6];
    const int* b2a       = (const int*)d_in[7];
    const int* b2revb    = (const int*)d_in[8];
    const int* mol_index = (const int*)d_in[9];
    float* out = (float*)d_out;

    const size_t SZ_BH2 = (size_t)NB * H * 2;       // 128 MB bf16 message buf
    const size_t SZ_AH4 = (size_t)NA * H * 4;       // 64 MB fp32 agg
    const size_t SZ_WP  = 256 * 256 * 2;            // 128 KB packed W_m
    const size_t NEEDED = 3 * SZ_BH2 + SZ_AH4 + SZ_WP;
    if (ws_size < NEEDED) return;  // diagnostic guard

    char* ws = (char*)d_ws;
    u32* inp   = (u32*)(ws);
    u32* msg1  = (u32*)(ws + SZ_BH2);
    u32* msg2  = (u32*)(ws + 2 * SZ_BH2);
    float* agg = (float*)(ws + 3 * SZ_BH2);
    uint4* Wp  = (uint4*)(ws + 3 * SZ_BH2 + SZ_AH4);
    float* ath = (float*)(ws + SZ_BH2);  // alias msg1 (dead by K4)

    // one-time W_m pack (bf16 fragment layout)
    k_pack_wm<<<32, 256, 0, stream>>>(W_m, Wp);

    // inp = f_bonds @ W_i (pre-activation, bf16); message0 = relu(inp) virtual
    k_gemm_wi<<<NB / 64, 256, 0, stream>>>(f_bonds, W_i, inp);

    // step 1
    k_agg<true><<<NA / 4, 256, 0, stream>>>(inp, a2b, agg);
    k_msg_update<true><<<NB / 64, 256, 0, stream>>>(inp, agg, inp, b2a, b2revb, Wp, msg1);

    // step 2
    k_agg<false><<<NA / 4, 256, 0, stream>>>(msg1, a2b, agg);
    k_msg_update<false><<<NB / 64, 256, 0, stream>>>(inp, agg, msg1, b2a, b2revb, Wp, msg2);

    // atom aggregation + W_a + relu
    k_agg<false><<<NA / 4, 256, 0, stream>>>(msg2, a2b, agg);
    k_atomh<<<NA / 32, 256, 0, stream>>>(f_atoms, agg, W_a, b_a, ath);

    // per-molecule mean readout
    k_readout<<<NM, 256, 0, stream>>>(ath, mol_index, out);
}

// Round 4
// 662.773 us; speedup vs baseline: 2.2547x; 1.3504x over previous
//
#include <hip/hip_runtime.h>
#include <cstdint>

#define NA 65536
#define NB 262144
#define MAXNB 6
#define H 256
#define BF 147
#define AF 133
#define NM 2048

typedef unsigned int u32;
typedef __attribute__((ext_vector_type(8))) short bf16x8;
typedef __attribute__((ext_vector_type(4))) float f32x4;

// bf16 helpers (manual, RNE)
__device__ __forceinline__ u32 pack_bf2(float a, float b) {
    u32 ua = __float_as_uint(a); ua = (ua + 0x7FFFu + ((ua >> 16) & 1u)) >> 16;
    u32 ub = __float_as_uint(b); ub = (ub + 0x7FFFu + ((ub >> 16) & 1u)) >> 16;
    return ua | (ub << 16);
}
__device__ __forceinline__ unsigned short bf1(float a) {
    u32 ua = __float_as_uint(a); return (unsigned short)((ua + 0x7FFFu + ((ua >> 16) & 1u)) >> 16);
}
__device__ __forceinline__ float bf_lo(u32 u) { return __uint_as_float(u << 16); }
__device__ __forceinline__ float bf_hi(u32 u) { return __uint_as_float(u & 0xFFFF0000u); }

// ---------------------------------------------------------------------------
// K0: generic weight pack W[K][256] fp32 -> bf16 fragment layout.
// Wp[kbg*256+col] holds 8 bf16 {W[kbg*8+j][col]}, zero-padded past K.
// grid = ceil(Kpad/8) blocks of 256.
// ---------------------------------------------------------------------------
__global__ __launch_bounds__(256) void k_pack_w(const float* __restrict__ W,
                                                uint4* __restrict__ Wp, int K) {
    int t = blockIdx.x * 256 + threadIdx.x;
    int kbg = t >> 8, col = t & 255;
    int k0 = kbg * 8;
    float x[8];
#pragma unroll
    for (int j = 0; j < 8; ++j)
        x[j] = (k0 + j < K) ? W[(size_t)(k0 + j) * 256 + col] : 0.f;
    uint4 o;
    o.x = pack_bf2(x[0], x[1]); o.y = pack_bf2(x[2], x[3]);
    o.z = pack_bf2(x[4], x[5]); o.w = pack_bf2(x[6], x[7]);
    Wp[t] = o;
}

// ---------------------------------------------------------------------------
// K1 (MFMA): inp[NB,256] = f_bonds[NB,147] @ W_i[147,256] -> bf16 (pre-act)
// K padded 147->160 (5 steps). A-tile LDS stride 336B (no conflict: 212w%32=20).
// ---------------------------------------------------------------------------
__global__ __launch_bounds__(256) void k_gemm_wi(const float* __restrict__ X,
                                                 const uint4* __restrict__ Wp,
                                                 u32* __restrict__ outb) {
    __shared__ char xs[64 * 512];  // A-region stride 336 (21504B); transpose 32768B
    const int blk = blockIdx.x;
    const int tid = threadIdx.x;
    const int lane = tid & 63, wv = tid >> 6;
    const int rlo = lane & 15, g = lane >> 4;
    const float* src = X + (size_t)blk * 64 * BF;
    for (int idx = tid; idx < 64 * 160; idx += 256) {
        int r = idx / 160, c = idx - r * 160;
        float v = (c < BF) ? src[r * BF + c] : 0.f;
        *(unsigned short*)(xs + r * 336 + c * 2) = bf1(v);
    }
    __syncthreads();
    f32x4 acc[4][4] = {};
#pragma unroll
    for (int kb = 0; kb < 5; ++kb) {
        bf16x8 af[4], bfr[4];
#pragma unroll
        for (int rb = 0; rb < 4; ++rb) {
            int row = rb * 16 + rlo;
            af[rb] = *(const bf16x8*)(xs + row * 336 + (kb * 4 + g) * 16);
        }
#pragma unroll
        for (int cb = 0; cb < 4; ++cb) {
            uint4 w = Wp[(size_t)(kb * 4 + g) * 256 + wv * 64 + cb * 16 + rlo];
            bfr[cb] = *(const bf16x8*)&w;
        }
#pragma unroll
        for (int rb = 0; rb < 4; ++rb)
#pragma unroll
            for (int cb = 0; cb < 4; ++cb)
                acc[rb][cb] = __builtin_amdgcn_mfma_f32_16x16x32_bf16(
                    af[rb], bfr[cb], acc[rb][cb], 0, 0, 0);
    }
    __syncthreads();
#pragma unroll
    for (int rb = 0; rb < 4; ++rb)
#pragma unroll
        for (int cb = 0; cb < 4; ++cb)
#pragma unroll
            for (int r = 0; r < 4; ++r)
                ((unsigned short*)xs)[(rb * 16 + g * 4 + r) * 256 + wv * 64 + cb * 16 + rlo] =
                    bf1(acc[rb][cb][r]);
    __syncthreads();
#pragma unroll
    for (int i = 0; i < 8; ++i) {
        int e = (i * 256 + tid) * 8;
        int row = e >> 8, col = e & 255;
        uint4 dv = *(const uint4*)(xs + row * 512 + col * 2);
        *(uint4*)&outb[(((size_t)blk * 64 + row) * 256 + col) >> 1] = dv;
    }
}

// ---------------------------------------------------------------------------
// K2: aggb[a,:] = sum_j msg(a2b[a][j])[:]  (bf16 in, bf16 out)
// ---------------------------------------------------------------------------
template <bool RELU_SRC>
__global__ __launch_bounds__(256) void k_agg(const u32* __restrict__ msgb,
                                             const int* __restrict__ a2b,
                                             u32* __restrict__ aggb) {
    const int tid = threadIdx.x;
    const int lane = tid & 63, wv = tid >> 6;
    const int a = blockIdx.x * 4 + wv;
    float4 s = {0.f, 0.f, 0.f, 0.f};
#pragma unroll
    for (int j = 0; j < MAXNB; ++j) {
        int b = a2b[a * MAXNB + j];
        uint2 mv = *(const uint2*)&msgb[(size_t)b * 128 + lane * 2];
        float e0 = bf_lo(mv.x), e1 = bf_hi(mv.x), e2 = bf_lo(mv.y), e3 = bf_hi(mv.y);
        if (RELU_SRC) {
            e0 = fmaxf(e0, 0.f); e1 = fmaxf(e1, 0.f);
            e2 = fmaxf(e2, 0.f); e3 = fmaxf(e3, 0.f);
        }
        s.x += e0; s.y += e1; s.z += e2; s.w += e3;
    }
    uint2 o;
    o.x = pack_bf2(s.x, s.y); o.y = pack_bf2(s.z, s.w);
    *(uint2*)&aggb[(size_t)a * 128 + lane * 2] = o;
}

// ---------------------------------------------------------------------------
// K3 (MFMA): msg_out = relu(inp + (agg[b2a] - msg(b2revb)) @ W_m)
// ---------------------------------------------------------------------------
template <bool RELU_SRC>
__global__ __launch_bounds__(256) void k_msg_update(
    const u32* __restrict__ inpb, const u32* __restrict__ aggb,
    const u32* __restrict__ msgb_in, const int* __restrict__ b2a,
    const int* __restrict__ b2revb, const uint4* __restrict__ Wp,
    u32* __restrict__ msgb_out) {
    __shared__ char xs[64 * 512];  // 32 KB bf16 [64][256]
    const int blk = blockIdx.x;
    const int tid = threadIdx.x;
    const int lane = tid & 63, wv = tid >> 6;
    const int rlo = lane & 15, g = lane >> 4;

    for (int r = wv; r < 64; r += 4) {
        const int b = blk * 64 + r;
        const int a = b2a[b];
        const int rb_ = b2revb[b];
        uint2 gv = *(const uint2*)&aggb[(size_t)a * 128 + lane * 2];
        uint2 mv = *(const uint2*)&msgb_in[(size_t)rb_ * 128 + lane * 2];
        float m0 = bf_lo(mv.x), m1 = bf_hi(mv.x), m2 = bf_lo(mv.y), m3 = bf_hi(mv.y);
        if (RELU_SRC) {
            m0 = fmaxf(m0, 0.f); m1 = fmaxf(m1, 0.f);
            m2 = fmaxf(m2, 0.f); m3 = fmaxf(m3, 0.f);
        }
        uint2 pk;
        pk.x = pack_bf2(bf_lo(gv.x) - m0, bf_hi(gv.x) - m1);
        pk.y = pack_bf2(bf_lo(gv.y) - m2, bf_hi(gv.y) - m3);
        int schunk = (lane >> 1) ^ (r & 7);
        *(uint2*)(xs + r * 512 + (schunk << 4) + (lane & 1) * 8) = pk;
    }
    __syncthreads();

    f32x4 acc[4][4] = {};
#pragma unroll
    for (int kb = 0; kb < 8; ++kb) {
        bf16x8 af[4], bfr[4];
#pragma unroll
        for (int rb = 0; rb < 4; ++rb) {
            int row = rb * 16 + rlo;
            int schunk = (kb * 4 + g) ^ (row & 7);
            af[rb] = *(const bf16x8*)(xs + row * 512 + (schunk << 4));
        }
#pragma unroll
        for (int cb = 0; cb < 4; ++cb) {
            uint4 w = Wp[(size_t)(kb * 4 + g) * 256 + wv * 64 + cb * 16 + rlo];
            bfr[cb] = *(const bf16x8*)&w;
        }
#pragma unroll
        for (int rb = 0; rb < 4; ++rb)
#pragma unroll
            for (int cb = 0; cb < 4; ++cb)
                acc[rb][cb] = __builtin_amdgcn_mfma_f32_16x16x32_bf16(
                    af[rb], bfr[cb], acc[rb][cb], 0, 0, 0);
    }
    __syncthreads();

#pragma unroll
    for (int rb = 0; rb < 4; ++rb)
#pragma unroll
        for (int cb = 0; cb < 4; ++cb)
#pragma unroll
            for (int r = 0; r < 4; ++r)
                ((unsigned short*)xs)[(rb * 16 + g * 4 + r) * 256 + wv * 64 + cb * 16 + rlo] =
                    bf1(acc[rb][cb][r]);
    __syncthreads();

#pragma unroll
    for (int i = 0; i < 8; ++i) {
        int e = (i * 256 + tid) * 8;
        int row = e >> 8, col = e & 255;
        uint4 dv = *(const uint4*)(xs + row * 512 + col * 2);
        size_t go = ((size_t)blk * 64 + row) * 256 + col;
        uint4 iv = *(const uint4*)&inpb[go >> 1];
        uint4 ov;
        ov.x = pack_bf2(fmaxf(bf_lo(dv.x) + bf_lo(iv.x), 0.f),
                        fmaxf(bf_hi(dv.x) + bf_hi(iv.x), 0.f));
        ov.y = pack_bf2(fmaxf(bf_lo(dv.y) + bf_lo(iv.y), 0.f),
                        fmaxf(bf_hi(dv.y) + bf_hi(iv.y), 0.f));
        ov.z = pack_bf2(fmaxf(bf_lo(dv.z) + bf_lo(iv.z), 0.f),
                        fmaxf(bf_hi(dv.z) + bf_hi(iv.z), 0.f));
        ov.w = pack_bf2(fmaxf(bf_lo(dv.w) + bf_lo(iv.w), 0.f),
                        fmaxf(bf_hi(dv.w) + bf_hi(iv.w), 0.f));
        *(uint4*)&msgb_out[go >> 1] = ov;
    }
}

// ---------------------------------------------------------------------------
// K4 (MFMA): atom_h = relu([f_atoms | a_message] @ W_a + b_a) -> bf16
// K = 389 padded to 416 (13 steps). A-tile stride 848B (212w%32=20, ok).
// ---------------------------------------------------------------------------
__global__ __launch_bounds__(256) void k_atomh(
    const float* __restrict__ f_atoms, const unsigned short* __restrict__ amsgb,
    const uint4* __restrict__ Wp, const float* __restrict__ ba,
    u32* __restrict__ athb) {
    __shared__ char xs[64 * 848];  // 54272B; transpose region (32768B) fits inside
    const int blk = blockIdx.x;
    const int tid = threadIdx.x;
    const int lane = tid & 63, wv = tid >> 6;
    const int rlo = lane & 15, g = lane >> 4;
    for (int idx = tid; idx < 64 * 416; idx += 256) {
        int r = idx / 416, c = idx - r * 416;
        int gr = blk * 64 + r;
        float v;
        if (c < AF) v = f_atoms[(size_t)gr * AF + c];
        else if (c < AF + 256) {
            u32 u = amsgb[(size_t)gr * 256 + (c - AF)];
            v = __uint_as_float(u << 16);
        } else v = 0.f;
        *(unsigned short*)(xs + r * 848 + c * 2) = bf1(v);
    }
    __syncthreads();
    f32x4 acc[4][4] = {};
#pragma unroll
    for (int kb = 0; kb < 13; ++kb) {
        bf16x8 af[4], bfr[4];
#pragma unroll
        for (int rb = 0; rb < 4; ++rb) {
            int row = rb * 16 + rlo;
            af[rb] = *(const bf16x8*)(xs + row * 848 + (kb * 4 + g) * 16);
        }
#pragma unroll
        for (int cb = 0; cb < 4; ++cb) {
            uint4 w = Wp[(size_t)(kb * 4 + g) * 256 + wv * 64 + cb * 16 + rlo];
            bfr[cb] = *(const bf16x8*)&w;
        }
#pragma unroll
        for (int rb = 0; rb < 4; ++rb)
#pragma unroll
            for (int cb = 0; cb < 4; ++cb)
                acc[rb][cb] = __builtin_amdgcn_mfma_f32_16x16x32_bf16(
                    af[rb], bfr[cb], acc[rb][cb], 0, 0, 0);
    }
    __syncthreads();
    float bcol[4];
#pragma unroll
    for (int cb = 0; cb < 4; ++cb) bcol[cb] = ba[wv * 64 + cb * 16 + rlo];
#pragma unroll
    for (int rb = 0; rb < 4; ++rb)
#pragma unroll
        for (int cb = 0; cb < 4; ++cb)
#pragma unroll
            for (int r = 0; r < 4; ++r)
                ((unsigned short*)xs)[(rb * 16 + g * 4 + r) * 256 + wv * 64 + cb * 16 + rlo] =
                    bf1(fmaxf(acc[rb][cb][r] + bcol[cb], 0.f));
    __syncthreads();
#pragma unroll
    for (int i = 0; i < 8; ++i) {
        int e = (i * 256 + tid) * 8;
        int row = e >> 8, col = e & 255;
        uint4 dv = *(const uint4*)(xs + row * 512 + col * 2);
        *(uint4*)&athb[(((size_t)blk * 64 + row) * 256 + col) >> 1] = dv;
    }
}

// ---------------------------------------------------------------------------
// K5: per-molecule mean readout (atom_h bf16); mol_index sorted -> bin search.
// ---------------------------------------------------------------------------
__global__ __launch_bounds__(256) void k_readout(const unsigned short* __restrict__ athb,
                                                 const int* __restrict__ mol_index,
                                                 float* __restrict__ out) {
    __shared__ int s_lo, s_hi;
    const int m = blockIdx.x;
    const int tid = threadIdx.x;
    if (tid == 0) {
        int lo = 0, hi = NA;
        while (lo < hi) { int mid = (lo + hi) >> 1; if (mol_index[mid] < m) lo = mid + 1; else hi = mid; }
        s_lo = lo;
        int lo2 = lo, hi2 = NA;
        while (lo2 < hi2) { int mid = (lo2 + hi2) >> 1; if (mol_index[mid] < m + 1) lo2 = mid + 1; else hi2 = mid; }
        s_hi = lo2;
    }
    __syncthreads();
    const int lo = s_lo, hi = s_hi;
    float s = 0.f;
    for (int a = lo; a < hi; ++a) {
        u32 u = athb[(size_t)a * 256 + tid];
        s += __uint_as_float(u << 16);
    }
    float cnt = (float)(hi - lo);
    out[(size_t)m * 256 + tid] = s / fmaxf(cnt, 1.0f);
}

// ---------------------------------------------------------------------------
extern "C" void kernel_launch(void* const* d_in, const int* in_sizes, int n_in,
                              void* d_out, int out_size, void* d_ws, size_t ws_size,
                              hipStream_t stream) {
    const float* f_atoms = (const float*)d_in[0];
    const float* f_bonds = (const float*)d_in[1];
    const float* W_i     = (const float*)d_in[2];
    const float* W_m     = (const float*)d_in[3];
    const float* W_a     = (const float*)d_in[4];
    const float* b_a     = (const float*)d_in[5];
    const int* a2b       = (const int*)d_in[6];
    const int* b2a       = (const int*)d_in[7];
    const int* b2revb    = (const int*)d_in[8];
    const int* mol_index = (const int*)d_in[9];
    float* out = (float*)d_out;

    const size_t SZ_BH2 = (size_t)NB * H * 2;   // 128 MB bf16 message buf
    const size_t SZ_AG2 = (size_t)NA * H * 2;   // 32 MB bf16 agg
    const size_t SZ_WPM = 32 * 256 * 16;        // 128 KB
    const size_t SZ_WPI = 20 * 256 * 16;        // 80 KB
    const size_t SZ_WPA = 52 * 256 * 16;        // 208 KB
    const size_t NEEDED = 3 * SZ_BH2 + SZ_AG2 + SZ_WPM + SZ_WPI + SZ_WPA;  // ~437 MB
    if (ws_size < NEEDED) return;  // diagnostic guard

    char* ws = (char*)d_ws;
    u32* inp    = (u32*)(ws);
    u32* msg1   = (u32*)(ws + SZ_BH2);
    u32* msg2   = (u32*)(ws + 2 * SZ_BH2);
    u32* aggb   = (u32*)(ws + 3 * SZ_BH2);
    uint4* WpM  = (uint4*)(ws + 3 * SZ_BH2 + SZ_AG2);
    uint4* WpI  = (uint4*)(ws + 3 * SZ_BH2 + SZ_AG2 + SZ_WPM);
    uint4* WpA  = (uint4*)(ws + 3 * SZ_BH2 + SZ_AG2 + SZ_WPM + SZ_WPI);
    u32* athb   = msg1;  // alias msg1 (dead by K4)

    // one-time weight packs (bf16 fragment layout, zero-padded K)
    k_pack_w<<<32, 256, 0, stream>>>(W_m, WpM, 256);
    k_pack_w<<<20, 256, 0, stream>>>(W_i, WpI, BF);
    k_pack_w<<<52, 256, 0, stream>>>(W_a, WpA, AF + H);

    // inp = f_bonds @ W_i (pre-activation, bf16); message0 = relu(inp) virtual
    k_gemm_wi<<<NB / 64, 256, 0, stream>>>(f_bonds, WpI, inp);

    // step 1
    k_agg<true><<<NA / 4, 256, 0, stream>>>(inp, a2b, aggb);
    k_msg_update<true><<<NB / 64, 256, 0, stream>>>(inp, aggb, inp, b2a, b2revb, WpM, msg1);

    // step 2
    k_agg<false><<<NA / 4, 256, 0, stream>>>(msg1, a2b, aggb);
    k_msg_update<false><<<NB / 64, 256, 0, stream>>>(inp, aggb, msg1, b2a, b2revb, WpM, msg2);

    // atom aggregation + W_a + relu
    k_agg<false><<<NA / 4, 256, 0, stream>>>(msg2, a2b, aggb);
    k_atomh<<<NA / 64, 256, 0, stream>>>(f_atoms, (const unsigned short*)aggb, WpA, b_a, athb);

    // per-molecule mean readout
    k_readout<<<NM, 256, 0, stream>>>((const unsigned short*)athb, mol_index, out);
}

// Round 5
// 584.466 us; speedup vs baseline: 2.5568x; 1.1340x over previous
//
#include <hip/hip_runtime.h>
#include <cstdint>

#define NA 65536
#define NB 262144
#define MAXNB 6
#define H 256
#define BF 147
#define AF 133
#define NM 2048

typedef unsigned int u32;
typedef __attribute__((ext_vector_type(8))) short bf16x8;
typedef __attribute__((ext_vector_type(4))) float f32x4;

// bf16 helpers (manual, RNE)
__device__ __forceinline__ u32 pack_bf2(float a, float b) {
    u32 ua = __float_as_uint(a); ua = (ua + 0x7FFFu + ((ua >> 16) & 1u)) >> 16;
    u32 ub = __float_as_uint(b); ub = (ub + 0x7FFFu + ((ub >> 16) & 1u)) >> 16;
    return ua | (ub << 16);
}
__device__ __forceinline__ unsigned short bf1(float a) {
    u32 ua = __float_as_uint(a); return (unsigned short)((ua + 0x7FFFu + ((ua >> 16) & 1u)) >> 16);
}
__device__ __forceinline__ float bf_lo(u32 u) { return __uint_as_float(u << 16); }
__device__ __forceinline__ float bf_hi(u32 u) { return __uint_as_float(u & 0xFFFF0000u); }

// ---------------------------------------------------------------------------
// K0: generic weight pack W[K][256] fp32 -> bf16 fragment layout (zero-pad K).
// ---------------------------------------------------------------------------
__global__ __launch_bounds__(256) void k_pack_w(const float* __restrict__ W,
                                                uint4* __restrict__ Wp, int K) {
    int t = blockIdx.x * 256 + threadIdx.x;
    int kbg = t >> 8, col = t & 255;
    int k0 = kbg * 8;
    float x[8];
#pragma unroll
    for (int j = 0; j < 8; ++j)
        x[j] = (k0 + j < K) ? W[(size_t)(k0 + j) * 256 + col] : 0.f;
    uint4 o;
    o.x = pack_bf2(x[0], x[1]); o.y = pack_bf2(x[2], x[3]);
    o.z = pack_bf2(x[4], x[5]); o.w = pack_bf2(x[6], x[7]);
    Wp[t] = o;
}

// ---------------------------------------------------------------------------
// K0b: f_bonds fp32 [NB][147] -> padded bf16 Xp [NB][160] (rows 320B, 64B-aligned)
// thread t handles 4 cols of one row; coalesced reads, aligned 8B stores.
// ---------------------------------------------------------------------------
__global__ __launch_bounds__(256) void k_prepad(const float* __restrict__ X,
                                                u32* __restrict__ Xp) {
    int t = blockIdx.x * 256 + threadIdx.x;     // [0, NB*40)
    int r = t / 40, c4 = t - r * 40;
    int c = c4 * 4;
    const float* row = X + (size_t)r * BF;
    float v0 = (c + 0 < BF) ? row[c + 0] : 0.f;
    float v1 = (c + 1 < BF) ? row[c + 1] : 0.f;
    float v2 = (c + 2 < BF) ? row[c + 2] : 0.f;
    float v3 = (c + 3 < BF) ? row[c + 3] : 0.f;
    uint2 o; o.x = pack_bf2(v0, v1); o.y = pack_bf2(v2, v3);
    *(uint2*)&Xp[(size_t)r * 80 + c4 * 2] = o;
}

// ---------------------------------------------------------------------------
// K1 (MFMA): inp = Xp(bf16,[NB][160]) @ W_i -> bf16 (pre-act)
// A-fragments read DIRECTLY from global (16 rows x 4 chunks = 16 full 64B
// lines per wave-load; 4 waves L1-absorbed). LDS only for output transpose.
// ---------------------------------------------------------------------------
__global__ __launch_bounds__(256) void k_gemm_wi(const u32* __restrict__ Xp,
                                                 const uint4* __restrict__ Wp,
                                                 u32* __restrict__ outb) {
    __shared__ char xs[64 * 512];  // output transpose only
    const int blk = blockIdx.x;
    const int tid = threadIdx.x;
    const int lane = tid & 63, wv = tid >> 6;
    const int rlo = lane & 15, g = lane >> 4;
    f32x4 acc[4][4] = {};
#pragma unroll
    for (int kb = 0; kb < 5; ++kb) {
        bf16x8 af[4], bfr[4];
#pragma unroll
        for (int rb = 0; rb < 4; ++rb) {
            int row = blk * 64 + rb * 16 + rlo;
            af[rb] = *(const bf16x8*)&Xp[(size_t)row * 80 + (kb * 4 + g) * 4];
        }
#pragma unroll
        for (int cb = 0; cb < 4; ++cb) {
            uint4 w = Wp[(size_t)(kb * 4 + g) * 256 + wv * 64 + cb * 16 + rlo];
            bfr[cb] = *(const bf16x8*)&w;
        }
#pragma unroll
        for (int rb = 0; rb < 4; ++rb)
#pragma unroll
            for (int cb = 0; cb < 4; ++cb)
                acc[rb][cb] = __builtin_amdgcn_mfma_f32_16x16x32_bf16(
                    af[rb], bfr[cb], acc[rb][cb], 0, 0, 0);
    }
#pragma unroll
    for (int rb = 0; rb < 4; ++rb)
#pragma unroll
        for (int cb = 0; cb < 4; ++cb)
#pragma unroll
            for (int r = 0; r < 4; ++r)
                ((unsigned short*)xs)[(rb * 16 + g * 4 + r) * 256 + wv * 64 + cb * 16 + rlo] =
                    bf1(acc[rb][cb][r]);
    __syncthreads();
#pragma unroll
    for (int i = 0; i < 8; ++i) {
        int e = (i * 256 + tid) * 8;
        int row = e >> 8, col = e & 255;
        uint4 dv = *(const uint4*)(xs + row * 512 + col * 2);
        *(uint4*)&outb[(((size_t)blk * 64 + row) * 256 + col) >> 1] = dv;
    }
}

// ---------------------------------------------------------------------------
// K2: aggb[a,:] = sum_j msg(a2b[a][j])[:]  (bf16 in, bf16 out)
// ---------------------------------------------------------------------------
template <bool RELU_SRC>
__global__ __launch_bounds__(256) void k_agg(const u32* __restrict__ msgb,
                                             const int* __restrict__ a2b,
                                             u32* __restrict__ aggb) {
    const int tid = threadIdx.x;
    const int lane = tid & 63, wv = tid >> 6;
    const int a = blockIdx.x * 4 + wv;
    float4 s = {0.f, 0.f, 0.f, 0.f};
#pragma unroll
    for (int j = 0; j < MAXNB; ++j) {
        int b = a2b[a * MAXNB + j];
        uint2 mv = *(const uint2*)&msgb[(size_t)b * 128 + lane * 2];
        float e0 = bf_lo(mv.x), e1 = bf_hi(mv.x), e2 = bf_lo(mv.y), e3 = bf_hi(mv.y);
        if (RELU_SRC) {
            e0 = fmaxf(e0, 0.f); e1 = fmaxf(e1, 0.f);
            e2 = fmaxf(e2, 0.f); e3 = fmaxf(e3, 0.f);
        }
        s.x += e0; s.y += e1; s.z += e2; s.w += e3;
    }
    uint2 o;
    o.x = pack_bf2(s.x, s.y); o.y = pack_bf2(s.z, s.w);
    *(uint2*)&aggb[(size_t)a * 128 + lane * 2] = o;
}

// ---------------------------------------------------------------------------
// K3 (MFMA): msg_out = relu(inp + (agg[b2a] - msg(b2revb)) @ W_m)
// ---------------------------------------------------------------------------
template <bool RELU_SRC>
__global__ __launch_bounds__(256) void k_msg_update(
    const u32* __restrict__ inpb, const u32* __restrict__ aggb,
    const u32* __restrict__ msgb_in, const int* __restrict__ b2a,
    const int* __restrict__ b2revb, const uint4* __restrict__ Wp,
    u32* __restrict__ msgb_out) {
    __shared__ char xs[64 * 512];  // 32 KB bf16 [64][256]
    const int blk = blockIdx.x;
    const int tid = threadIdx.x;
    const int lane = tid & 63, wv = tid >> 6;
    const int rlo = lane & 15, g = lane >> 4;

    for (int r = wv; r < 64; r += 4) {
        const int b = blk * 64 + r;
        const int a = b2a[b];
        const int rb_ = b2revb[b];
        uint2 gv = *(const uint2*)&aggb[(size_t)a * 128 + lane * 2];
        uint2 mv = *(const uint2*)&msgb_in[(size_t)rb_ * 128 + lane * 2];
        float m0 = bf_lo(mv.x), m1 = bf_hi(mv.x), m2 = bf_lo(mv.y), m3 = bf_hi(mv.y);
        if (RELU_SRC) {
            m0 = fmaxf(m0, 0.f); m1 = fmaxf(m1, 0.f);
            m2 = fmaxf(m2, 0.f); m3 = fmaxf(m3, 0.f);
        }
        uint2 pk;
        pk.x = pack_bf2(bf_lo(gv.x) - m0, bf_hi(gv.x) - m1);
        pk.y = pack_bf2(bf_lo(gv.y) - m2, bf_hi(gv.y) - m3);
        int schunk = (lane >> 1) ^ (r & 7);
        *(uint2*)(xs + r * 512 + (schunk << 4) + (lane & 1) * 8) = pk;
    }
    __syncthreads();

    f32x4 acc[4][4] = {};
#pragma unroll
    for (int kb = 0; kb < 8; ++kb) {
        bf16x8 af[4], bfr[4];
#pragma unroll
        for (int rb = 0; rb < 4; ++rb) {
            int row = rb * 16 + rlo;
            int schunk = (kb * 4 + g) ^ (row & 7);
            af[rb] = *(const bf16x8*)(xs + row * 512 + (schunk << 4));
        }
#pragma unroll
        for (int cb = 0; cb < 4; ++cb) {
            uint4 w = Wp[(size_t)(kb * 4 + g) * 256 + wv * 64 + cb * 16 + rlo];
            bfr[cb] = *(const bf16x8*)&w;
        }
#pragma unroll
        for (int rb = 0; rb < 4; ++rb)
#pragma unroll
            for (int cb = 0; cb < 4; ++cb)
                acc[rb][cb] = __builtin_amdgcn_mfma_f32_16x16x32_bf16(
                    af[rb], bfr[cb], acc[rb][cb], 0, 0, 0);
    }
    __syncthreads();

#pragma unroll
    for (int rb = 0; rb < 4; ++rb)
#pragma unroll
        for (int cb = 0; cb < 4; ++cb)
#pragma unroll
            for (int r = 0; r < 4; ++r)
                ((unsigned short*)xs)[(rb * 16 + g * 4 + r) * 256 + wv * 64 + cb * 16 + rlo] =
                    bf1(acc[rb][cb][r]);
    __syncthreads();

#pragma unroll
    for (int i = 0; i < 8; ++i) {
        int e = (i * 256 + tid) * 8;
        int row = e >> 8, col = e & 255;
        uint4 dv = *(const uint4*)(xs + row * 512 + col * 2);
        size_t go = ((size_t)blk * 64 + row) * 256 + col;
        uint4 iv = *(const uint4*)&inpb[go >> 1];
        uint4 ov;
        ov.x = pack_bf2(fmaxf(bf_lo(dv.x) + bf_lo(iv.x), 0.f),
                        fmaxf(bf_hi(dv.x) + bf_hi(iv.x), 0.f));
        ov.y = pack_bf2(fmaxf(bf_lo(dv.y) + bf_lo(iv.y), 0.f),
                        fmaxf(bf_hi(dv.y) + bf_hi(iv.y), 0.f));
        ov.z = pack_bf2(fmaxf(bf_lo(dv.z) + bf_lo(iv.z), 0.f),
                        fmaxf(bf_hi(dv.z) + bf_hi(iv.z), 0.f));
        ov.w = pack_bf2(fmaxf(bf_lo(dv.w) + bf_lo(iv.w), 0.f),
                        fmaxf(bf_hi(dv.w) + bf_hi(iv.w), 0.f));
        *(uint4*)&msgb_out[go >> 1] = ov;
    }
}

// ---------------------------------------------------------------------------
// K4 (MFMA): atom_h = relu([f_atoms | a_message] @ W_a + b_a) -> bf16
// ---------------------------------------------------------------------------
__global__ __launch_bounds__(256) void k_atomh(
    const float* __restrict__ f_atoms, const unsigned short* __restrict__ amsgb,
    const uint4* __restrict__ Wp, const float* __restrict__ ba,
    u32* __restrict__ athb) {
    __shared__ char xs[64 * 848];
    const int blk = blockIdx.x;
    const int tid = threadIdx.x;
    const int lane = tid & 63, wv = tid >> 6;
    const int rlo = lane & 15, g = lane >> 4;
    for (int idx = tid; idx < 64 * 416; idx += 256) {
        int r = idx / 416, c = idx - r * 416;
        int gr = blk * 64 + r;
        float v;
        if (c < AF) v = f_atoms[(size_t)gr * AF + c];
        else if (c < AF + 256) {
            u32 u = amsgb[(size_t)gr * 256 + (c - AF)];
            v = __uint_as_float(u << 16);
        } else v = 0.f;
        *(unsigned short*)(xs + r * 848 + c * 2) = bf1(v);
    }
    __syncthreads();
    f32x4 acc[4][4] = {};
#pragma unroll
    for (int kb = 0; kb < 13; ++kb) {
        bf16x8 af[4], bfr[4];
#pragma unroll
        for (int rb = 0; rb < 4; ++rb) {
            int row = rb * 16 + rlo;
            af[rb] = *(const bf16x8*)(xs + row * 848 + (kb * 4 + g) * 16);
        }
#pragma unroll
        for (int cb = 0; cb < 4; ++cb) {
            uint4 w = Wp[(size_t)(kb * 4 + g) * 256 + wv * 64 + cb * 16 + rlo];
            bfr[cb] = *(const bf16x8*)&w;
        }
#pragma unroll
        for (int rb = 0; rb < 4; ++rb)
#pragma unroll
            for (int cb = 0; cb < 4; ++cb)
                acc[rb][cb] = __builtin_amdgcn_mfma_f32_16x16x32_bf16(
                    af[rb], bfr[cb], acc[rb][cb], 0, 0, 0);
    }
    __syncthreads();
    float bcol[4];
#pragma unroll
    for (int cb = 0; cb < 4; ++cb) bcol[cb] = ba[wv * 64 + cb * 16 + rlo];
#pragma unroll
    for (int rb = 0; rb < 4; ++rb)
#pragma unroll
        for (int cb = 0; cb < 4; ++cb)
#pragma unroll
            for (int r = 0; r < 4; ++r)
                ((unsigned short*)xs)[(rb * 16 + g * 4 + r) * 256 + wv * 64 + cb * 16 + rlo] =
                    bf1(fmaxf(acc[rb][cb][r] + bcol[cb], 0.f));
    __syncthreads();
#pragma unroll
    for (int i = 0; i < 8; ++i) {
        int e = (i * 256 + tid) * 8;
        int row = e >> 8, col = e & 255;
        uint4 dv = *(const uint4*)(xs + row * 512 + col * 2);
        *(uint4*)&athb[(((size_t)blk * 64 + row) * 256 + col) >> 1] = dv;
    }
}

// ---------------------------------------------------------------------------
// K5: per-molecule mean readout (atom_h bf16); mol_index sorted -> bin search.
// ---------------------------------------------------------------------------
__global__ __launch_bounds__(256) void k_readout(const unsigned short* __restrict__ athb,
                                                 const int* __restrict__ mol_index,
                                                 float* __restrict__ out) {
    __shared__ int s_lo, s_hi;
    const int m = blockIdx.x;
    const int tid = threadIdx.x;
    if (tid == 0) {
        int lo = 0, hi = NA;
        while (lo < hi) { int mid = (lo + hi) >> 1; if (mol_index[mid] < m) lo = mid + 1; else hi = mid; }
        s_lo = lo;
        int lo2 = lo, hi2 = NA;
        while (lo2 < hi2) { int mid = (lo2 + hi2) >> 1; if (mol_index[mid] < m + 1) lo2 = mid + 1; else hi2 = mid; }
        s_hi = lo2;
    }
    __syncthreads();
    const int lo = s_lo, hi = s_hi;
    float s = 0.f;
    for (int a = lo; a < hi; ++a) {
        u32 u = athb[(size_t)a * 256 + tid];
        s += __uint_as_float(u << 16);
    }
    float cnt = (float)(hi - lo);
    out[(size_t)m * 256 + tid] = s / fmaxf(cnt, 1.0f);
}

// ---------------------------------------------------------------------------
extern "C" void kernel_launch(void* const* d_in, const int* in_sizes, int n_in,
                              void* d_out, int out_size, void* d_ws, size_t ws_size,
                              hipStream_t stream) {
    const float* f_atoms = (const float*)d_in[0];
    const float* f_bonds = (const float*)d_in[1];
    const float* W_i     = (const float*)d_in[2];
    const float* W_m     = (const float*)d_in[3];
    const float* W_a     = (const float*)d_in[4];
    const float* b_a     = (const float*)d_in[5];
    const int* a2b       = (const int*)d_in[6];
    const int* b2a       = (const int*)d_in[7];
    const int* b2revb    = (const int*)d_in[8];
    const int* mol_index = (const int*)d_in[9];
    float* out = (float*)d_out;

    const size_t SZ_BH2 = (size_t)NB * H * 2;   // 128 MB bf16 message buf
    const size_t SZ_AG2 = (size_t)NA * H * 2;   // 32 MB bf16 agg
    const size_t SZ_WPM = 32 * 256 * 16;
    const size_t SZ_WPI = 20 * 256 * 16;
    const size_t SZ_WPA = 52 * 256 * 16;
    const size_t NEEDED = 3 * SZ_BH2 + SZ_AG2 + SZ_WPM + SZ_WPI + SZ_WPA;  // ~437 MB
    if (ws_size < NEEDED) return;  // diagnostic guard

    char* ws = (char*)d_ws;
    u32* inp    = (u32*)(ws);
    u32* msg1   = (u32*)(ws + SZ_BH2);
    u32* msg2   = (u32*)(ws + 2 * SZ_BH2);
    u32* aggb   = (u32*)(ws + 3 * SZ_BH2);
    uint4* WpM  = (uint4*)(ws + 3 * SZ_BH2 + SZ_AG2);
    uint4* WpI  = (uint4*)(ws + 3 * SZ_BH2 + SZ_AG2 + SZ_WPM);
    uint4* WpA  = (uint4*)(ws + 3 * SZ_BH2 + SZ_AG2 + SZ_WPM + SZ_WPI);
    u32* Xp     = msg1;  // 84 MB padded bf16 f_bonds; aliases msg1 (dead until step 1)
    u32* athb   = msg1;  // alias msg1 (dead by K4)

    // one-time packs
    k_pack_w<<<32, 256, 0, stream>>>(W_m, WpM, 256);
    k_pack_w<<<20, 256, 0, stream>>>(W_i, WpI, BF);
    k_pack_w<<<52, 256, 0, stream>>>(W_a, WpA, AF + H);
    k_prepad<<<NB * 40 / 256, 256, 0, stream>>>(f_bonds, Xp);

    // inp = f_bonds @ W_i (pre-activation, bf16); message0 = relu(inp) virtual
    k_gemm_wi<<<NB / 64, 256, 0, stream>>>(Xp, WpI, inp);

    // step 1 (overwrites msg1 -> Xp becomes dead exactly here)
    k_agg<true><<<NA / 4, 256, 0, stream>>>(inp, a2b, aggb);
    k_msg_update<true><<<NB / 64, 256, 0, stream>>>(inp, aggb, inp, b2a, b2revb, WpM, msg1);

    // step 2
    k_agg<false><<<NA / 4, 256, 0, stream>>>(msg1, a2b, aggb);
    k_msg_update<false><<<NB / 64, 256, 0, stream>>>(inp, aggb, msg1, b2a, b2revb, WpM, msg2);

    // atom aggregation + W_a + relu
    k_agg<false><<<NA / 4, 256, 0, stream>>>(msg2, a2b, aggb);
    k_atomh<<<NA / 64, 256, 0, stream>>>(f_atoms, (const unsigned short*)aggb, WpA, b_a, athb);

    // per-molecule mean readout
    k_readout<<<NM, 256, 0, stream>>>((const unsigned short*)athb, mol_index, out);
}